// Round 8
// baseline (208.411 us; speedup 1.0000x reference)
//
#include <hip/hip_runtime.h>

// Problem constants
#define BATCH 32
#define CIN   256
#define CR    8
#define HDIM  56
#define WDIM  56
#define HW    3136          // 56*56
#define COUT  44            // 8 z_norm + 36 interactions

#define NCG   8             // cin groups (one per k1a block per image)
#define CPG   32            // cin per group
#define NPIX  (BATCH*HW)    // 100352
#define ZFLT  (NPIX*CR)     // 802816 floats in z
#define F4PP  784           // float4 per (b,cin) plane = 3136/4

// upper-triangular pair table for the 36 interaction channels
__device__ __constant__ const int PI36[36] =
    {0,0,0,0,0,0,0,0, 1,1,1,1,1,1,1, 2,2,2,2,2,2, 3,3,3,3,3, 4,4,4,4, 5,5,5, 6,6, 7};
__device__ __constant__ const int PJ36[36] =
    {0,1,2,3,4,5,6,7, 1,2,3,4,5,6,7, 2,3,4,5,6,7, 3,4,5,6,7, 4,5,6,7, 5,6,7, 6,7, 7};

// ---------------------------------------------------------------------------
// k0: tiny prep. Transpose wr -> wrT[cin][8] (so k1a's per-cin weights are 2
// uniform s_load_dwordx4 instead of 8 scattered s_loads) and precompute the
// BN inv/shift vectors.
// ---------------------------------------------------------------------------
__global__ __launch_bounds__(256) void k0_prep(
    const float* __restrict__ wr, const float* __restrict__ gamma,
    const float* __restrict__ beta, const float* __restrict__ mean,
    const float* __restrict__ var,
    float* __restrict__ wrT, float* __restrict__ invc, float* __restrict__ shc)
{
    const int t = threadIdx.x;               // = cin
#pragma unroll
    for (int c = 0; c < CR; ++c) wrT[t * CR + c] = wr[c * CIN + t];
    if (t < CR) {
        const float iv = gamma[t] / sqrtf(var[t] + 1e-5f);
        invc[t] = iv;
        shc[t]  = beta[t] - mean[t] * iv;
    }
}

// ---------------------------------------------------------------------------
// k1a: SEQUENTIAL-STREAM partial reduce. All previous k1 variants gathered
// 256B-1KB chunks at 12.5KB stride (thousands of live strided streams) and
// pinned at 2.45 TB/s regardless of width/occupancy -> DRAM row-thrash
// hypothesis (256B channel interleave makes every touch a new row; request
// width can't fix it, only temporal address locality can).
//   Block (b,cg) = image b x cin [32cg,32cg+32): reads a CONTIGUOUS 401KB
// span of x front-to-back, exactly like the 6.29 TB/s m13 copy pattern.
//   832 threads (13 waves): thread t<784 owns pixels 4t..4t+3; per cin it
// loads ONE float4 (block instrs sweep the 12.5KB plane in address order),
// FMAs into acc[4px][8ch] (registers only, no LDS), 4-deep load pipeline
// (~3KB in flight/wave x 13 waves/CU). Partials written coalesced to
// part[cg][gp][ch]. Grid = 256 blocks = 1/CU.
// ---------------------------------------------------------------------------
__global__ __launch_bounds__(832) void k1a_partial(
    const float* __restrict__ x, const float* __restrict__ wrT,
    float* __restrict__ part)
{
    const int blk = blockIdx.x;              // 0..255
    const int b   = blk >> 3;                // image
    const int cg  = blk & 7;                 // cin group
    const int t   = threadIdx.x;             // 0..831
    const bool act = (t < F4PP);             // 784 active threads

    const float4* __restrict__ xs4 = reinterpret_cast<const float4*>(
        x + ((size_t)b * CIN + (size_t)cg * CPG) * HW);      // 401KB span
    const float4* __restrict__ wt4 = reinterpret_cast<const float4*>(
        wrT + (size_t)cg * CPG * CR);        // 2 float4 per cin, uniform

    float acc[4][CR];
#pragma unroll
    for (int q = 0; q < 4; ++q)
#pragma unroll
        for (int c = 0; c < CR; ++c) acc[q][c] = 0.f;

    float4 buf[4];
    if (act) {
#pragma unroll
        for (int i = 0; i < 4; ++i) buf[i] = xs4[i * F4PP + t];
    }

    for (int k0 = 0; k0 < CPG; k0 += 4) {
#pragma unroll
        for (int i = 0; i < 4; ++i) {
            const int cin = k0 + i;
            const float4 w0 = wt4[2 * cin];
            const float4 w1 = wt4[2 * cin + 1];
            const float4 v  = buf[i];
            const float px[4] = {v.x, v.y, v.z, v.w};
            const float wc[CR] = {w0.x, w0.y, w0.z, w0.w,
                                  w1.x, w1.y, w1.z, w1.w};
#pragma unroll
            for (int q = 0; q < 4; ++q)
#pragma unroll
                for (int c = 0; c < CR; ++c)
                    acc[q][c] = fmaf(px[q], wc[c], acc[q][c]);
            // refill this buffer for cin+4 (stays in flight while the next
            // three buffers are consumed)
            if (act && (k0 + 4 + i) < CPG)
                buf[i] = xs4[(size_t)(k0 + 4 + i) * F4PP + t];
        }
    }

    if (act) {
        // part[cg][b*HW + 4t .. +3][ch] : 128B contiguous per thread,
        // 8KB per wave -> fully coalesced
        float* pp = part + (size_t)cg * ZFLT + ((size_t)b * HW + 4 * t) * CR;
#pragma unroll
        for (int q = 0; q < 4; ++q) {
            *reinterpret_cast<float4*>(pp + q * CR) =
                make_float4(acc[q][0], acc[q][1], acc[q][2], acc[q][3]);
            *reinterpret_cast<float4*>(pp + q * CR + 4) =
                make_float4(acc[q][4], acc[q][5], acc[q][6], acc[q][7]);
        }
    }
}

// ---------------------------------------------------------------------------
// k1b: reduce the 8 cin-group partials + BN + ReLU -> z (channels-last).
// 8 sequential strided streams (3.2MB apart) + 1 write stream, all float4.
// 29MB total ~ 5-6us at streaming BW.
// ---------------------------------------------------------------------------
__global__ __launch_bounds__(512) void k1b_reduce_bn(
    const float* __restrict__ part, const float* __restrict__ invc,
    const float* __restrict__ shc, float* __restrict__ z)
{
    const int v = blockIdx.x * 512 + threadIdx.x;    // 0..200703 (float4 id)
    const float4* __restrict__ p4 = reinterpret_cast<const float4*>(part);

    float4 s = p4[v];
#pragma unroll
    for (int cg = 1; cg < NCG; ++cg) {
        const float4 t4 = p4[(size_t)cg * (ZFLT / 4) + v];
        s.x += t4.x; s.y += t4.y; s.z += t4.z; s.w += t4.w;
    }
    const int c0 = (v & 1) * 4;                      // channels c0..c0+3
    const float4 iv = *reinterpret_cast<const float4*>(invc + c0);
    const float4 sh = *reinterpret_cast<const float4*>(shc + c0);
    float4 r;
    r.x = fmaxf(fmaf(s.x, iv.x, sh.x), 0.f);
    r.y = fmaxf(fmaf(s.y, iv.y, sh.y), 0.f);
    r.z = fmaxf(fmaf(s.z, iv.z, sh.z), 0.f);
    r.w = fmaxf(fmaf(s.w, iv.w, sh.w), 0.f);
    reinterpret_cast<float4*>(z)[v] = r;
}

// ---------------------------------------------------------------------------
// k2 (FROZEN from R6/R7, measured ~5.5-7us): depthwise 3x3 * scale + L2
// norms + 36 pairwise products -> 44 channels. 4 waves over the same 64
// pixels; each wave redundantly computes conv+norms and writes an
// 11-channel slice.
// ---------------------------------------------------------------------------
__global__ __launch_bounds__(256) void k2_dw_norm_inter(
    const float* __restrict__ z, const float* __restrict__ wdw,
    const float* __restrict__ scale, float* __restrict__ out)
{
    const int lane = threadIdx.x & 63;
    const int wv   = __builtin_amdgcn_readfirstlane(threadIdx.x >> 6); // 0..3
    const int t = blockIdx.x * 64 + lane;          // global pixel id
    const int b = t / HW;
    const int p = t - b * HW;
    const int h = p / WDIM;
    const int w = p - h * WDIM;

    const float* __restrict__ zimg = z + (size_t)b * HW * CR;

    float4 n0[9], n1[9];
    float  mk[9];
#pragma unroll
    for (int dy = -1; dy <= 1; ++dy) {
#pragma unroll
        for (int dx = -1; dx <= 1; ++dx) {
            const int k  = (dy + 1) * 3 + (dx + 1);
            const int hh = h + dy, ww = w + dx;
            const bool ok = (hh >= 0) & (hh < HDIM) & (ww >= 0) & (ww < WDIM);
            const int hc = min(max(hh, 0), HDIM - 1);
            const int wc = min(max(ww, 0), WDIM - 1);
            mk[k] = ok ? 1.0f : 0.0f;
            const float* zn = zimg + (size_t)(hc * WDIM + wc) * CR;
            n0[k] = reinterpret_cast<const float4*>(zn)[0];
            n1[k] = reinterpret_cast<const float4*>(zn)[1];
        }
    }

    const float zc[CR] = {n0[4].x, n0[4].y, n0[4].z, n0[4].w,
                          n1[4].x, n1[4].y, n1[4].z, n1[4].w};

    float tw[CR];
#pragma unroll
    for (int c = 0; c < CR; ++c) tw[c] = 0.f;
#pragma unroll
    for (int k = 0; k < 9; ++k) {
        const float nv[CR] = {n0[k].x, n0[k].y, n0[k].z, n0[k].w,
                              n1[k].x, n1[k].y, n1[k].z, n1[k].w};
#pragma unroll
        for (int c = 0; c < CR; ++c)
            tw[c] = fmaf(nv[c] * mk[k], wdw[c * 9 + k], tw[c]);
    }

    float s1 = 0.f, s2 = 0.f;
#pragma unroll
    for (int c = 0; c < CR; ++c) {
        tw[c] *= scale[c];
        s1 = fmaf(zc[c], zc[c], s1);
        s2 = fmaf(tw[c], tw[c], s2);
    }
    const float r1 = 1.0f / fmaxf(sqrtf(s1), 1e-6f);
    const float r2 = 1.0f / fmaxf(sqrtf(s2), 1e-6f);

    float a[CR], tb[CR];
#pragma unroll
    for (int c = 0; c < CR; ++c) { a[c] = zc[c] * r1; tb[c] = tw[c] * r2; }

    float* op = out + (size_t)b * COUT * HW + p;
#pragma unroll
    for (int c = 0; c < COUT; ++c) {
        if ((c / 11) == wv) {
            const float val = (c < CR) ? a[c]
                                       : a[PI36[c - CR]] * tb[PJ36[c - CR]];
            op[(size_t)c * HW] = val;
        }
    }
}

extern "C" void kernel_launch(void* const* d_in, const int* in_sizes, int n_in,
                              void* d_out, int out_size, void* d_ws, size_t ws_size,
                              hipStream_t stream) {
    const float* x     = (const float*)d_in[0];
    const float* wr    = (const float*)d_in[1];
    const float* gamma = (const float*)d_in[2];
    const float* beta  = (const float*)d_in[3];
    const float* mean  = (const float*)d_in[4];
    const float* var   = (const float*)d_in[5];
    const float* wdw   = (const float*)d_in[6];
    const float* scale = (const float*)d_in[7];
    float* out = (float*)d_out;

    // workspace layout (floats): z | part[8] | wrT | invc | shc  (~28.9MB)
    float* ws   = (float*)d_ws;
    float* z    = ws;                        // 802816
    float* part = ws + ZFLT;                 // 8 * 802816
    float* wrT  = ws + (size_t)ZFLT * 9;     // 2048
    float* invc = wrT + 2048;                // 8
    float* shc  = invc + 8;                  // 8

    k0_prep<<<1, 256, 0, stream>>>(wr, gamma, beta, mean, var, wrT, invc, shc);
    k1a_partial<<<BATCH * NCG, 832, 0, stream>>>(x, wrT, part);
    k1b_reduce_bn<<<ZFLT / 4 / 512, 512, 0, stream>>>(part, invc, shc, z);
    k2_dw_norm_inter<<<NPIX / 64, 256, 0, stream>>>(z, wdw, scale, out);
}

// Round 9
// 166.430 us; speedup vs baseline: 1.2522x; 1.2522x over previous
//
#include <hip/hip_runtime.h>

// Problem constants
#define BATCH 32
#define CIN   256
#define CR    8
#define HDIM  56
#define WDIM  56
#define HW    3136          // 56*56 = 49*64 (waves never straddle batch rows)
#define COUT  44            // 8 z_norm + 36 interactions

// upper-triangular pair table for the 36 interaction channels
__device__ __constant__ const int PI36[36] =
    {0,0,0,0,0,0,0,0, 1,1,1,1,1,1,1, 2,2,2,2,2,2, 3,3,3,3,3, 4,4,4,4, 5,5,5, 6,6, 7};
__device__ __constant__ const int PJ36[36] =
    {0,1,2,3,4,5,6,7, 1,2,3,4,5,6,7, 2,3,4,5,6,7, 3,4,5,6,7, 4,5,6,7, 5,6,7, 6,7, 7};

// ---------------------------------------------------------------------------
// Kernel 1: 1x1 conv reduce (256->8) + BN + ReLU.
// Structure = R4's directly-measured 42us version (512 thr = 8 waves over 64
// px, wave w reduces cin [32w,32w+32), 2-buffer 8-deep pipeline, 16KB LDS
// combine). NEW: x loads are NON-TEMPORAL (nt flag -> no L2/L3 allocation).
// Rationale: every read kernel pins at 2.0-2.5 TB/s while write-only fills
// hit 6.9 TB/s; WRITE_SIZE anomalies (+41..57MB vs our stores in R3/R5/R8)
// show our read-misses evict the poison fill's dirty L2/L3 lines -- the
// interleaved allocate+writeback halves effective read BW. nt reads skip
// allocation entirely. x is read exactly once, so caching it has no value.
// z (re-read 9x by k2) keeps normal cached stores.
// ---------------------------------------------------------------------------
__global__ __launch_bounds__(512, 8) void k1_reduce_bn_relu(
    const float* __restrict__ x, const float* __restrict__ wr,
    const float* __restrict__ gamma, const float* __restrict__ beta,
    const float* __restrict__ mean, const float* __restrict__ var,
    float* __restrict__ z)
{
    const int tid  = threadIdx.x;
    const int lane = tid & 63;
    const int wv   = __builtin_amdgcn_readfirstlane(tid >> 6);   // 0..7
    const int pix0 = blockIdx.x * 64;
    const int gp   = pix0 + lane;
    const int b    = gp / HW;
    const int p    = gp - b * HW;
    const int cin0 = wv * 32;

    const float* __restrict__ xq =
        x + (size_t)b * CIN * HW + (size_t)cin0 * HW + p;

    float acc[CR];
#pragma unroll
    for (int c = 0; c < CR; ++c) acc[c] = 0.f;

    float xa[8], xb[8];
    auto loadx = [&](float (&arr)[8], int base) {
#pragma unroll
        for (int j = 0; j < 8; ++j)
            arr[j] = __builtin_nontemporal_load(
                         xq + (size_t)(base + j) * HW);   // nt: no L2/L3 alloc
    };
    auto consume = [&](const float (&arr)[8], int base) {
#pragma unroll
        for (int j = 0; j < 8; ++j) {
            const int cin = cin0 + base + j;              // wave-uniform
#pragma unroll
            for (int c = 0; c < CR; ++c)
                acc[c] = fmaf(arr[j], wr[c * CIN + cin], acc[c]);
        }
    };

    loadx(xa, 0);
    loadx(xb, 8);            // 16 loads in flight
    consume(xa, 0);
    loadx(xa, 16);           // issued while xb in flight
    consume(xb, 8);
    loadx(xb, 24);
    consume(xa, 16);
    consume(xb, 24);

    __shared__ float pacc[8][64][CR];            // 16 KB
#pragma unroll
    for (int c = 0; c < CR; c += 4)
        *reinterpret_cast<float4*>(&pacc[wv][lane][c]) =
            make_float4(acc[c], acc[c + 1], acc[c + 2], acc[c + 3]);
    __syncthreads();

    // 512 outputs (64 px * 8 ch), 512 threads -> 1 each; store coalesced.
    const int c  = tid & 7;
    const int px = tid >> 3;
    float s = 0.f;
#pragma unroll
    for (int w = 0; w < 8; ++w) s += pacc[w][px][c];
    const float inv = gamma[c] / sqrtf(var[c] + 1e-5f);
    const float sh  = beta[c] - mean[c] * inv;
    z[(size_t)pix0 * CR + tid] = fmaxf(fmaf(s, inv, sh), 0.f);  // cached (k2 re-reads)
}

// ---------------------------------------------------------------------------
// Kernel 2 (R6 slice structure, measured ~5.5-7us): depthwise 3x3 * scale +
// L2 norms + 36 pairwise products -> 44 channels. 4 waves over the same 64
// pixels; each wave redundantly computes conv+norms (tap loads L1/L2-shared)
// and writes an 11-channel slice. NEW: out stores are NON-TEMPORAL (out is
// written once, never read; avoids dirtying L2/L3 and the associated
// eviction traffic seen as 4.2x WRITE amplification in R3/R5).
// ---------------------------------------------------------------------------
__global__ __launch_bounds__(256) void k2_dw_norm_inter(
    const float* __restrict__ z, const float* __restrict__ wdw,
    const float* __restrict__ scale, float* __restrict__ out)
{
    const int lane = threadIdx.x & 63;
    const int wv   = __builtin_amdgcn_readfirstlane(threadIdx.x >> 6); // 0..3
    const int t = blockIdx.x * 64 + lane;          // global pixel id
    const int b = t / HW;
    const int p = t - b * HW;
    const int h = p / WDIM;
    const int w = p - h * WDIM;

    const float* __restrict__ zimg = z + (size_t)b * HW * CR;

    // issue all 9 tap loads first (static reg indices, one waitcnt)
    float4 n0[9], n1[9];
    float  mk[9];
#pragma unroll
    for (int dy = -1; dy <= 1; ++dy) {
#pragma unroll
        for (int dx = -1; dx <= 1; ++dx) {
            const int k  = (dy + 1) * 3 + (dx + 1);
            const int hh = h + dy, ww = w + dx;
            const bool ok = (hh >= 0) & (hh < HDIM) & (ww >= 0) & (ww < WDIM);
            const int hc = min(max(hh, 0), HDIM - 1);
            const int wc = min(max(ww, 0), WDIM - 1);
            mk[k] = ok ? 1.0f : 0.0f;
            const float* zn = zimg + (size_t)(hc * WDIM + wc) * CR;
            n0[k] = reinterpret_cast<const float4*>(zn)[0];
            n1[k] = reinterpret_cast<const float4*>(zn)[1];
        }
    }

    const float zc[CR] = {n0[4].x, n0[4].y, n0[4].z, n0[4].w,
                          n1[4].x, n1[4].y, n1[4].z, n1[4].w};

    float tw[CR];
#pragma unroll
    for (int c = 0; c < CR; ++c) tw[c] = 0.f;
#pragma unroll
    for (int k = 0; k < 9; ++k) {
        const float nv[CR] = {n0[k].x, n0[k].y, n0[k].z, n0[k].w,
                              n1[k].x, n1[k].y, n1[k].z, n1[k].w};
#pragma unroll
        for (int c = 0; c < CR; ++c)
            tw[c] = fmaf(nv[c] * mk[k], wdw[c * 9 + k], tw[c]);
    }

    float s1 = 0.f, s2 = 0.f;
#pragma unroll
    for (int c = 0; c < CR; ++c) {
        tw[c] *= scale[c];
        s1 = fmaf(zc[c], zc[c], s1);
        s2 = fmaf(tw[c], tw[c], s2);
    }
    const float r1 = 1.0f / fmaxf(sqrtf(s1), 1e-6f);
    const float r2 = 1.0f / fmaxf(sqrtf(s2), 1e-6f);

    float a[CR], tb[CR];
#pragma unroll
    for (int c = 0; c < CR; ++c) { a[c] = zc[c] * r1; tb[c] = tw[c] * r2; }

    // this wave's 11-channel slice of the 44 outputs (compile-time idx),
    // non-temporal stores (write-once data)
    float* op = out + (size_t)b * COUT * HW + p;
#pragma unroll
    for (int c = 0; c < COUT; ++c) {
        if ((c / 11) == wv) {
            const float val = (c < CR) ? a[c]
                                       : a[PI36[c - CR]] * tb[PJ36[c - CR]];
            __builtin_nontemporal_store(val, op + (size_t)c * HW);
        }
    }
}

extern "C" void kernel_launch(void* const* d_in, const int* in_sizes, int n_in,
                              void* d_out, int out_size, void* d_ws, size_t ws_size,
                              hipStream_t stream) {
    const float* x     = (const float*)d_in[0];
    const float* wr    = (const float*)d_in[1];
    const float* gamma = (const float*)d_in[2];
    const float* beta  = (const float*)d_in[3];
    const float* mean  = (const float*)d_in[4];
    const float* var   = (const float*)d_in[5];
    const float* wdw   = (const float*)d_in[6];
    const float* scale = (const float*)d_in[7];
    float* out = (float*)d_out;
    float* z   = (float*)d_ws;   // BATCH*HW*CR floats = 3.21 MB, channels-last

    const int npix = BATCH * HW;              // 100352
    k1_reduce_bn_relu<<<npix / 64, 512, 0, stream>>>(x, wr, gamma, beta, mean, var, z);
    k2_dw_norm_inter<<<npix / 64, 256, 0, stream>>>(z, wdw, scale, out);
}